// Round 4
// baseline (266.821 us; speedup 1.0000x reference)
//
#include <hip/hip_runtime.h>
#include <hip/hip_bf16.h>
#include <math.h>

// ---------------------------------------------------------------------------
// PSI_47931835024047: x@W_omega -> chunked phase cumsum/rotation -> LN ->
//                     W1+gelu -> W2 + residual.
// B=4 S=4096 D=512 C=64. All GEMMs bf16 MFMA.
// R13: H2 = in-order issue backpressure. R12's phase issued 12 ds_read back-
//      to-back then 32 MFMA; the DS queue (96 reqs/CU at phase start) stalls
//      the wave mid-read-issue, blocking its MFMA issues -> LDS and MFMA
//      pipes serialize (33% MfmaUtil ~= 1242/3360). Fix: interleave at fine
//      grain -- 8 groups of {1 stage-load | 3 ds_reads; 4 MFMA}, pinned by
//      sched_barrier(0). Same ops/fences/accumulation set => same numerics.
//      (This is m196's "fine ds_read || G::load || MFMA interleave" lever.)
// ---------------------------------------------------------------------------

typedef __bf16 bf16x8 __attribute__((ext_vector_type(8)));
typedef __bf16 bf16x4 __attribute__((ext_vector_type(4)));
typedef __bf16 bf16x2 __attribute__((ext_vector_type(2)));
typedef float  f32x4  __attribute__((ext_vector_type(4)));

typedef __attribute__((address_space(1))) void* gas_ptr;
typedef __attribute__((address_space(3))) void* las_ptr;

// wave-uniform LDS base; each lane deposits 16 B at base + lane*16
__device__ __forceinline__ void load_lds16(const void* g, void* l) {
    __builtin_amdgcn_global_load_lds((gas_ptr)g, (las_ptr)l, 16, 0, 0);
}

// ---------------------------------------------------------------------------
// Fused prep: block ranges do (a) x->bf16 cast, (b) W_omega^T, (c) W1^T,
// (d) W2^T. One launch instead of four.
// ---------------------------------------------------------------------------
__device__ __forceinline__ void transpose_tile(const float* __restrict__ in,
                                               __bf16* __restrict__ out,
                                               int K, int N, int bx, int by,
                                               float (*tile)[33])
{
    const int tid = threadIdx.x;
    const int tx = tid & 31, ty = tid >> 5;       // (32, 8)
    const int n0 = bx * 32, k0 = by * 32;
    #pragma unroll
    for (int i = 0; i < 32; i += 8)
        tile[ty + i][tx] = in[(size_t)(k0 + ty + i) * N + n0 + tx];
    __syncthreads();
    #pragma unroll
    for (int i = 0; i < 32; i += 8)
        out[(size_t)(n0 + ty + i) * K + k0 + tx] = (__bf16)tile[tx][ty + i];
}

__global__ __launch_bounds__(256)
void prep_kernel(const float* __restrict__ x, __bf16* __restrict__ xb,
                 const float* __restrict__ W_omega, __bf16* __restrict__ womT,
                 const float* __restrict__ W1, __bf16* __restrict__ w1T,
                 const float* __restrict__ W2, __bf16* __restrict__ w2T)
{
    __shared__ float tile[32][33];
    const int bid = blockIdx.x;
    if (bid < 8192) {
        int i = bid * 256 + threadIdx.x;          // 2097152 float4's
        float4 v = ((const float4*)x)[i];
        bf16x4 o = { (__bf16)v.x, (__bf16)v.y, (__bf16)v.z, (__bf16)v.w };
        ((bf16x4*)xb)[i] = o;
    } else if (bid < 8448) {
        int t = bid - 8192;                       // 16 x 16
        transpose_tile(W_omega, womT, 512, 512, t & 15, t >> 4, tile);
    } else if (bid < 10496) {
        int t = bid - 8448;                       // 32 x 64
        transpose_tile(W1, w1T, 2048, 1024, t & 31, t >> 5, tile);
    } else {
        int t = bid - 10496;                      // 16 x 32
        transpose_tile(W2, w2T, 1024, 512, t & 15, t >> 4, tile);
    }
}

// ---------------------------------------------------------------------------
// bf16 MFMA GEMM (R7 structure): 128x128 tile, 4 waves, BK=64 double-buffered.
// Used for GEMM1 (MODE 0) and GEMM3 (MODE 2) where N=512 keeps 256^2 grids
// too small.
// ---------------------------------------------------------------------------
template<int MODE>
__global__ __launch_bounds__(256)
void gemm_kernel(const __bf16* __restrict__ A, const __bf16* __restrict__ Bt,
                 const float* __restrict__ bias, const __bf16* __restrict__ resid,
                 void* __restrict__ out, int M, int N, int K)
{
    __shared__ __bf16 As[2][128 * 64];
    __shared__ __bf16 Bs[2][128 * 64];

    const int tid     = threadIdx.x;
    const int tiles_n = N >> 7;                 // 4 or 8 (power of 2)
    const int ln_tn   = __ffs(tiles_n) - 1;
    const int per_m   = (M >> 7) >> 3;          // 128-row tiles per XCD

    const int xcd = blockIdx.x & 7;
    const int j   = blockIdx.x >> 3;
    const int tile_m = (xcd * per_m + (j >> ln_tn)) << 7;
    const int tile_n = (j & (tiles_n - 1)) << 7;

    const int wave = tid >> 6;
    const int lane = tid & 63;

    // staging map: lane l -> row (l>>3), chunk (l&7)^((l>>3)&7)
    const int srow = lane >> 3;                       // 0..7
    const int scol = ((lane & 7) ^ srow) << 3;        // elem offset in row

    const __bf16* Ags = A  + (size_t)(tile_m + wave * 32 + srow) * K + scol;
    const __bf16* Bgs = Bt + (size_t)(tile_n + wave * 32 + srow) * K + scol;

    const int m0 = (wave >> 1) << 6;
    const int n0 = (wave & 1) << 6;
    const int lr = lane & 15;
    const int q  = lane >> 4;
    const int l7 = lane & 7;
    const int fc0 = ((0 + q) ^ l7) << 3;   // swizzled elem offset, k-half 0
    const int fc1 = ((4 + q) ^ l7) << 3;   // swizzled elem offset, k-half 1

    f32x4 acc[4][4];
    #pragma unroll
    for (int i = 0; i < 4; ++i)
        #pragma unroll
        for (int jj = 0; jj < 4; ++jj)
            acc[i][jj] = (f32x4){0.f, 0.f, 0.f, 0.f};

    const int nIter = K >> 6;

    // prologue: stage tile 0 into buffer 0
    #pragma unroll
    for (int c = 0; c < 4; ++c) {
        load_lds16(Ags + (size_t)(c * 8) * K, &As[0][(wave * 32 + c * 8) * 64]);
        load_lds16(Bgs + (size_t)(c * 8) * K, &Bs[0][(wave * 32 + c * 8) * 64]);
    }

    for (int it = 0; it < nIter; ++it) {
        const int cur = it & 1;
        __syncthreads();   // drains prefetch issued last iter (aged thru MFMA)
        if (it + 1 < nIter) {
            const int nk = (it + 1) << 6;
            #pragma unroll
            for (int c = 0; c < 4; ++c) {
                load_lds16(Ags + nk + (size_t)(c * 8) * K, &As[cur ^ 1][(wave * 32 + c * 8) * 64]);
                load_lds16(Bgs + nk + (size_t)(c * 8) * K, &Bs[cur ^ 1][(wave * 32 + c * 8) * 64]);
            }
        }

        const __bf16* as = As[cur];
        const __bf16* bs = Bs[cur];
        // k-half 0
        {
            bf16x8 af[4], bq[4];
            #pragma unroll
            for (int i = 0; i < 4; ++i)
                af[i] = *(const bf16x8*)&as[(m0 + i * 16 + lr) * 64 + fc0];
            #pragma unroll
            for (int jj = 0; jj < 4; ++jj)
                bq[jj] = *(const bf16x8*)&bs[(n0 + jj * 16 + lr) * 64 + fc0];
            #pragma unroll
            for (int i = 0; i < 4; ++i)
                #pragma unroll
                for (int jj = 0; jj < 4; ++jj)
                    acc[i][jj] = __builtin_amdgcn_mfma_f32_16x16x32_bf16(af[i], bq[jj], acc[i][jj], 0, 0, 0);
        }
        // k-half 1
        {
            bf16x8 af[4], bq[4];
            #pragma unroll
            for (int i = 0; i < 4; ++i)
                af[i] = *(const bf16x8*)&as[(m0 + i * 16 + lr) * 64 + fc1];
            #pragma unroll
            for (int jj = 0; jj < 4; ++jj)
                bq[jj] = *(const bf16x8*)&bs[(n0 + jj * 16 + lr) * 64 + fc1];
            #pragma unroll
            for (int i = 0; i < 4; ++i)
                #pragma unroll
                for (int jj = 0; jj < 4; ++jj)
                    acc[i][jj] = __builtin_amdgcn_mfma_f32_16x16x32_bf16(af[i], bq[jj], acc[i][jj], 0, 0, 0);
        }
    }

    // epilogue — C/D layout: col = lane&15, row = (lane>>4)*4 + reg  [m89/m91]
    const int orow0 = tile_m + m0 + (q << 2);
    const int ocol0 = tile_n + n0 + lr;
    #pragma unroll
    for (int i = 0; i < 4; ++i) {
        #pragma unroll
        for (int jj = 0; jj < 4; ++jj) {
            const int col = ocol0 + jj * 16;
            const float bv = bias[col];
            #pragma unroll
            for (int r = 0; r < 4; ++r) {
                const int row = orow0 + i * 16 + r;
                float v = acc[i][jj][r] + bv;
                size_t idx = (size_t)row * N + col;
                if (MODE == 0) {
                    ((__bf16*)out)[idx] = (__bf16)v;
                } else if (MODE == 1) {
                    float g = 0.5f * v * (1.0f + erff(v * 0.70710678118654752f));
                    ((__bf16*)out)[idx] = (__bf16)g;
                } else {
                    ((float*)out)[idx] = v + (float)resid[idx];
                }
            }
        }
    }
}

// ---------------------------------------------------------------------------
// R13: 256x256-tile GEMM, 512 threads (8 waves, 2Mx4N), 4-slot k-slice ring,
// 2-deep register fragment pipeline, asm ds_read fragment loads, and a
// FINE-GRAINED per-phase interleave:
//
// Phase ks (steady state):
//   vmcnt(8); s_barrier
//   8 groups, sched_barrier(0)-pinned:
//     {1 global_load_lds (stage ks+4)            ; 4 MFMA (slice ks)}  x4
//     {3 asm ds_read_b128 (slice ks+1 frags)     ; 4 MFMA (slice ks)}  x4
//   lgkmcnt(0); sched_barrier(0)
// Max 3 LDS ops pending issue per wave before each MFMA burst -> no DS-queue
// backpressure in front of MFMA issue; LDS pipe drains under the MFMA pipe.
// Tail (last 6 phases) uses the guarded non-interleaved form with the exact
// R12 vmcnt countdown (8/4/0).
//
// Swizzle (both-sides involution, 0 conflicts measured R10-R12):
//   staging sigma = (lane&3)^((lane>>3)&3); read fslot = q4 ^ ((lane>>1)&3).
// Requires NKS even, >= 8 (K=2048: NKS=64). Accumulation set per phase
// unchanged => numerics identical to R10-R12.
// ---------------------------------------------------------------------------
template<int MODE>
__global__ __launch_bounds__(512, 1)
void gemm256_kernel(const __bf16* __restrict__ A, const __bf16* __restrict__ Bt,
                    const float* __restrict__ bias, void* __restrict__ out,
                    int M, int N, int K)
{
    __shared__ __bf16 As[4][256 * 32];
    __shared__ __bf16 Bs[4][256 * 32];

    const int tid  = threadIdx.x;
    const int wv   = tid >> 6;            // 0..7
    const int lane = tid & 63;
    const int wm   = wv >> 2;             // 0..1  (M half)
    const int wn   = wv & 3;              // 0..3  (N quarter)

    const int tiles_n = N >> 8;                    // 4 (power of 2)
    const int ln_tn   = __ffs(tiles_n) - 1;
    const int per_m   = (M >> 8) >> 3;             // 256-row tiles per XCD

    const int xcd = blockIdx.x & 7;
    const int j   = blockIdx.x >> 3;
    const int tile_m = (xcd * per_m + (j >> ln_tn)) << 8;
    const int tile_n = (j & (tiles_n - 1)) << 8;

    // --- staging constants ---------------------------------------------
    const int srow = 16 * wv + (lane >> 2);                       // 0..127
    const int sig8 = (((lane & 3) ^ ((lane >> 3) & 3)) << 3);     // elem off

    const __bf16* Ag = A  + (size_t)(tile_m + srow) * K + sig8;
    const __bf16* Bg = Bt + (size_t)(tile_n + srow) * K + sig8;
    const size_t rowK128 = (size_t)128 * K;
    const int lbase = wv * 512;            // wave-uniform LDS elem base

    // --- fragment-read constants ---------------------------------------
    const int lr    = lane & 15;           // row within 16-row fragment
    const int q4    = lane >> 4;           // logical 16B k-slot 0..3
    const int fslot = ((q4 ^ ((lane >> 1) & 3)) << 3);   // swizzled elem off
    const int arow0 = wm * 128 + lr;
    const int brow0 = wn * 64 + lr;

    // raw 32-bit LDS byte addresses of slot-0 fragments
    const unsigned ldsA0 = (unsigned)(size_t)(las_ptr)&As[0][0];
    const unsigned ldsB0 = (unsigned)(size_t)(las_ptr)&Bs[0][0];
    const unsigned asA = ldsA0 + (unsigned)((arow0 * 32 + fslot) << 1);
    const unsigned asB = ldsB0 + (unsigned)((brow0 * 32 + fslot) << 1);

    f32x4 acc[8][4];
    #pragma unroll
    for (int i = 0; i < 8; ++i)
        #pragma unroll
        for (int jj = 0; jj < 4; ++jj)
            acc[i][jj] = (f32x4){0.f, 0.f, 0.f, 0.f};

    const int NKS = K >> 5;                // k-slices of 32 (even, >= 8)

    auto stage = [&](int ks) {
        const int slot = ks & 3;
        const __bf16* ag = Ag + (ks << 5);
        const __bf16* bg = Bg + (ks << 5);
        load_lds16(ag,           &As[slot][lbase]);
        load_lds16(ag + rowK128, &As[slot][4096 + lbase]);
        load_lds16(bg,           &Bs[slot][lbase]);
        load_lds16(bg + rowK128, &Bs[slot][4096 + lbase]);
    };

    bf16x8 afA[8], bqA[4], afB[8], bqB[4];

#define DSR(d, a, o) asm volatile("ds_read_b128 %0, %1 offset:" o \
                                  : "=v"(d) : "v"(a))
#define SB __builtin_amdgcn_sched_barrier(0)
#define MM4(CAF, CBQ, I)                                                      \
    acc[I][0] = __builtin_amdgcn_mfma_f32_16x16x32_bf16(CAF[I], CBQ[0], acc[I][0], 0, 0, 0); \
    acc[I][1] = __builtin_amdgcn_mfma_f32_16x16x32_bf16(CAF[I], CBQ[1], acc[I][1], 0, 0, 0); \
    acc[I][2] = __builtin_amdgcn_mfma_f32_16x16x32_bf16(CAF[I], CBQ[2], acc[I][2], 0, 0, 0); \
    acc[I][3] = __builtin_amdgcn_mfma_f32_16x16x32_bf16(CAF[I], CBQ[3], acc[I][3], 0, 0, 0);

#define G256_READ(KS, NAF, NBQ)                                               \
    {                                                                         \
        const unsigned aA_ = asA + (unsigned)(((KS) & 3) << 14);              \
        const unsigned aB_ = asB + (unsigned)(((KS) & 3) << 14);              \
        DSR(NAF[0], aA_, "0");    DSR(NAF[1], aA_, "1024");                   \
        DSR(NAF[2], aA_, "2048"); DSR(NAF[3], aA_, "3072");                   \
        DSR(NAF[4], aA_, "4096"); DSR(NAF[5], aA_, "5120");                   \
        DSR(NAF[6], aA_, "6144"); DSR(NAF[7], aA_, "7168");                   \
        DSR(NBQ[0], aB_, "0");    DSR(NBQ[1], aB_, "1024");                   \
        DSR(NBQ[2], aB_, "2048"); DSR(NBQ[3], aB_, "3072");                   \
    }

// steady-state phase: requires ks+4 < NKS (stage valid) and NKS-1-ks >= 3
#define G256_PHASE_FULL(KS, CAF, CBQ, NAF, NBQ)                               \
    {                                                                         \
        const int ks_ = (KS);                                                 \
        asm volatile("s_waitcnt vmcnt(8)" ::: "memory");                      \
        __builtin_amdgcn_s_barrier();                                         \
        asm volatile("" ::: "memory");                                        \
        const int slot_ = (ks_ + 4) & 3;                                      \
        const __bf16* ag_ = Ag + ((ks_ + 4) << 5);                            \
        const __bf16* bg_ = Bg + ((ks_ + 4) << 5);                            \
        const unsigned aA_ = asA + (unsigned)(((ks_ + 1) & 3) << 14);         \
        const unsigned aB_ = asB + (unsigned)(((ks_ + 1) & 3) << 14);         \
        __builtin_amdgcn_s_setprio(1);                                        \
        load_lds16(ag_,           &As[slot_][lbase]);                         \
        MM4(CAF, CBQ, 0) SB;                                                  \
        load_lds16(ag_ + rowK128, &As[slot_][4096 + lbase]);                  \
        MM4(CAF, CBQ, 1) SB;                                                  \
        load_lds16(bg_,           &Bs[slot_][lbase]);                         \
        MM4(CAF, CBQ, 2) SB;                                                  \
        load_lds16(bg_ + rowK128, &Bs[slot_][4096 + lbase]);                  \
        MM4(CAF, CBQ, 3) SB;                                                  \
        DSR(NAF[0], aA_, "0"); DSR(NAF[1], aA_, "1024");                      \
        DSR(NAF[2], aA_, "2048");                                             \
        MM4(CAF, CBQ, 4) SB;                                                  \
        DSR(NAF[3], aA_, "3072"); DSR(NAF[4], aA_, "4096");                   \
        DSR(NAF[5], aA_, "5120");                                             \
        MM4(CAF, CBQ, 5) SB;                                                  \
        DSR(NAF[6], aA_, "6144"); DSR(NAF[7], aA_, "7168");                   \
        DSR(NBQ[0], aB_, "0");                                                \
        MM4(CAF, CBQ, 6) SB;                                                  \
        DSR(NBQ[1], aB_, "1024"); DSR(NBQ[2], aB_, "2048");                   \
        DSR(NBQ[3], aB_, "3072");                                             \
        MM4(CAF, CBQ, 7)                                                      \
        __builtin_amdgcn_s_setprio(0);                                        \
        asm volatile("s_waitcnt lgkmcnt(0)" ::: "memory");                    \
        __builtin_amdgcn_sched_barrier(0);                                    \
    }

// tail phase: guarded stages/reads, R12 vmcnt countdown
#define G256_PHASE_TAIL(KS, CAF, CBQ, NAF, NBQ)                               \
    {                                                                         \
        const int ks_ = (KS);                                                 \
        const int r_  = NKS - 1 - ks_;                                        \
        if (r_ >= 3)      asm volatile("s_waitcnt vmcnt(8)" ::: "memory");    \
        else if (r_ == 2) asm volatile("s_waitcnt vmcnt(4)" ::: "memory");    \
        else if (r_ == 1) asm volatile("s_waitcnt vmcnt(0)" ::: "memory");    \
        __builtin_amdgcn_s_barrier();                                         \
        asm volatile("" ::: "memory");                                        \
        if (ks_ + 4 < NKS) stage(ks_ + 4);                                    \
        if (ks_ + 1 < NKS) G256_READ(ks_ + 1, NAF, NBQ)                       \
        __builtin_amdgcn_s_setprio(1);                                        \
        _Pragma("unroll")                                                     \
        for (int i_ = 0; i_ < 8; ++i_)                                        \
            _Pragma("unroll")                                                 \
            for (int j_ = 0; j_ < 4; ++j_)                                    \
                acc[i_][j_] = __builtin_amdgcn_mfma_f32_16x16x32_bf16(        \
                    CAF[i_], CBQ[j_], acc[i_][j_], 0, 0, 0);                  \
        __builtin_amdgcn_s_setprio(0);                                        \
        asm volatile("s_waitcnt lgkmcnt(0)" ::: "memory");                    \
        __builtin_amdgcn_sched_barrier(0);                                    \
    }

    // prologue: slices 0..2 in flight, then certify slice 0 and preload its
    // fragments into set A (the ks=0 phase's "current" set).
    stage(0); stage(1); stage(2);
    asm volatile("s_waitcnt vmcnt(8)" ::: "memory");   // stage(0) retired
    __builtin_amdgcn_s_barrier();                      // slice 0 published
    asm volatile("" ::: "memory");
    stage(3);                                          // slot 3 (no conflict)
    G256_READ(0, afA, bqA)
    asm volatile("s_waitcnt lgkmcnt(0)" ::: "memory"); // drained before ks=0 barrier
    __builtin_amdgcn_sched_barrier(0);

    int ks = 0;
    for (; ks + 6 < NKS; ks += 2) {
        G256_PHASE_FULL(ks,     afA, bqA, afB, bqB)
        G256_PHASE_FULL(ks + 1, afB, bqB, afA, bqA)
    }
    for (; ks < NKS; ks += 2) {
        G256_PHASE_TAIL(ks,     afA, bqA, afB, bqB)
        G256_PHASE_TAIL(ks + 1, afB, bqB, afA, bqA)
    }

#undef G256_PHASE_FULL
#undef G256_PHASE_TAIL
#undef G256_READ
#undef MM4
#undef SB
#undef DSR

    // epilogue — C/D layout: col = lane&15, row = (lane>>4)*4 + reg
    const int orow0 = tile_m + wm * 128 + (q4 << 2);
    const int ocol0 = tile_n + wn * 64 + lr;
    #pragma unroll
    for (int i = 0; i < 8; ++i) {
        #pragma unroll
        for (int jj = 0; jj < 4; ++jj) {
            const int col = ocol0 + jj * 16;
            const float bv = bias[col];
            #pragma unroll
            for (int r = 0; r < 4; ++r) {
                const int row = orow0 + i * 16 + r;
                float v = acc[i][jj][r] + bv;
                if (MODE == 1) {
                    float g = 0.5f * v * (1.0f + erff(v * 0.70710678118654752f));
                    ((__bf16*)out)[(size_t)row * N + col] = (__bf16)g;
                } else {
                    ((__bf16*)out)[(size_t)row * N + col] = (__bf16)v;
                }
            }
        }
    }
}

// ---------------------------------------------------------------------------
// Per-chunk phase cumsum + rotation + running means + LayerNorm.
// ---------------------------------------------------------------------------
__global__ __launch_bounds__(512)
void scan_ln_kernel(const __bf16* __restrict__ xb, const __bf16* __restrict__ omega,
                    const float* __restrict__ log_scale,
                    const float* __restrict__ gamma, const float* __restrict__ beta,
                    __bf16* __restrict__ ctx)
{
    const int chunk = blockIdx.x;        // 0..255  (b*64 + n)
    const int d     = threadIdx.x;       // 0..511
    const int lane  = d & 63, wv = d >> 6;   // 8 waves
    const size_t base = (size_t)chunk * 64 * 512;

    const float scale = expf(log_scale[d]);
    const float g0 = gamma[d], g1 = gamma[512 + d], g2 = gamma[1024 + d], g3 = gamma[1536 + d];
    const float e0 = beta[d],  e1 = beta[512 + d],  e2 = beta[1024 + d],  e3 = beta[1536 + d];

    float phi = 0.f, scr = 0.f, sci = 0.f;
    __shared__ float red[2][16];         // [slot][8 sums | 8 sumsq]

    float om_n = (float)omega[base + d];
    float xv_n = (float)xb[base + d];

    for (int c = 0; c < 64; ++c) {
        const float om = om_n;
        const float xv = xv_n;
        if (c < 63) {
            om_n = (float)omega[base + (size_t)(c + 1) * 512 + d];
            xv_n = (float)xb[base + (size_t)(c + 1) * 512 + d];
        }
        phi += om * scale * rsqrtf((float)(c + 1));
        float sp, cp;
        __sincosf(phi, &sp, &cp);
        const float cr = xv * cp, ci = xv * sp;
        scr += cr; sci += ci;
        const float inv = 1.0f / (float)(c + 1);
        const float mr = scr * inv, mi = sci * inv;
        const float rr = mr * cp + mi * sp;
        const float ri = mi * cp - mr * sp;

        float s  = cr + ci + rr + ri;
        float s2 = cr * cr + ci * ci + rr * rr + ri * ri;
        #pragma unroll
        for (int o = 32; o > 0; o >>= 1) {
            s  += __shfl_down(s, o);
            s2 += __shfl_down(s2, o);
        }
        if (lane == 0) { red[c & 1][wv] = s; red[c & 1][8 + wv] = s2; }
        __syncthreads();
        float S = 0.f, S2 = 0.f;
        #pragma unroll
        for (int i = 0; i < 8; ++i) { S += red[c & 1][i]; S2 += red[c & 1][8 + i]; }
        const float mu   = S * (1.0f / 2048.0f);
        const float var  = S2 * (1.0f / 2048.0f) - mu * mu;
        const float rstd = rsqrtf(var + 1e-5f);

        const size_t ob = ((size_t)chunk * 64 + c) * 2048;
        ctx[ob + d]        = (__bf16)(((cr - mu) * rstd) * g0 + e0);
        ctx[ob + 512 + d]  = (__bf16)(((ci - mu) * rstd) * g1 + e1);
        ctx[ob + 1024 + d] = (__bf16)(((rr - mu) * rstd) * g2 + e2);
        ctx[ob + 1536 + d] = (__bf16)(((ri - mu) * rstd) * g3 + e3);
    }
}

// ---------------------------------------------------------------------------
// Workspace layout (bytes):
//   xb    @ 0          : 16,777,216  (16384x512 bf16)
//   womT  @ 16777216   : 524,288     (512x512 bf16, transposed)
//   w1T   @ 17301504   : 4,194,304   (1024x2048 bf16, transposed)
//   w2T   @ 21495808   : 1,048,576   (512x1024 bf16, transposed)
//   omega @ 22544384   : 16,777,216  (16384x512 bf16) — region reused as h
//   h     @ 22544384   : 33,554,432  (16384x1024 bf16)
//   ctx   @ 56098816   : 67,108,864  (16384x2048 bf16)
// ---------------------------------------------------------------------------
extern "C" void kernel_launch(void* const* d_in, const int* in_sizes, int n_in,
                              void* d_out, int out_size, void* d_ws, size_t ws_size,
                              hipStream_t stream)
{
    const float* x         = (const float*)d_in[0];
    const float* W_omega   = (const float*)d_in[1];
    const float* b_omega   = (const float*)d_in[2];
    const float* log_scale = (const float*)d_in[3];
    const float* ln_gamma  = (const float*)d_in[4];
    const float* ln_beta   = (const float*)d_in[5];
    const float* W1        = (const float*)d_in[6];
    const float* b1        = (const float*)d_in[7];
    const float* W2        = (const float*)d_in[8];
    const float* b2        = (const float*)d_in[9];
    float* out = (float*)d_out;

    char* ws = (char*)d_ws;
    __bf16* xb    = (__bf16*)(ws);
    __bf16* womT  = (__bf16*)(ws + 16777216);
    __bf16* w1T   = (__bf16*)(ws + 17301504);
    __bf16* w2T   = (__bf16*)(ws + 21495808);
    __bf16* omega = (__bf16*)(ws + 22544384);
    __bf16* hbuf  = (__bf16*)(ws + 22544384);   // reuses omega region
    __bf16* ctx   = (__bf16*)(ws + 56098816);

    // 1. fused cast + weight transposes (one launch)
    prep_kernel<<<11008, 256, 0, stream>>>(x, xb, W_omega, womT, W1, w1T, W2, w2T);

    // 2. omega = x @ W_omega + b_omega   (bf16 out)
    gemm_kernel<0><<<512, 256, 0, stream>>>(xb, womT, b_omega, nullptr, omega, 16384, 512, 512);

    // 3. chunk scan + LayerNorm -> ctx (bf16, 16384x2048)
    scan_ln_kernel<<<256, 512, 0, stream>>>(xb, omega, log_scale, ln_gamma, ln_beta, ctx);

    // 4. h = gelu(ctx @ W1 + b1)  (bf16 out) — R13 interleaved ring kernel
    gemm256_kernel<1><<<256, 512, 0, stream>>>(ctx, w1T, b1, hbuf, 16384, 1024, 2048);

    // 5. out = x + h @ W2 + b2    (fp32 out, bf16 residual)
    gemm_kernel<2><<<512, 256, 0, stream>>>(hbuf, w2T, b2, xb, out, 16384, 512, 1024);
}

// Round 5
// 262.577 us; speedup vs baseline: 1.0162x; 1.0162x over previous
//
#include <hip/hip_runtime.h>
#include <hip/hip_bf16.h>
#include <math.h>

// ---------------------------------------------------------------------------
// PSI_47931835024047: x@W_omega -> chunked phase cumsum/rotation -> LN ->
//                     W1+gelu -> W2 + residual.
// B=4 S=4096 D=512 C=64. All GEMMs bf16 MFMA.
// R14: GEMM2 rebuilt as a barrier-LIGHT group schedule (m201-derived, race
//      proof in comments): BK=64 K-tiles, 2 LDS buffers, 4 phases/group with
//      NO internal barriers -- waves desynchronize within a group so read
//      regions of some waves overlap MFMA regions of others (the overlap the
//      R10-R13 lockstep ring structurally could not express). One vmcnt(0)+
//      s_barrier per group (2 per 8 phases, vs 8 before).
// ---------------------------------------------------------------------------

typedef __bf16 bf16x8 __attribute__((ext_vector_type(8)));
typedef __bf16 bf16x4 __attribute__((ext_vector_type(4)));
typedef __bf16 bf16x2 __attribute__((ext_vector_type(2)));
typedef float  f32x4  __attribute__((ext_vector_type(4)));

typedef __attribute__((address_space(1))) void* gas_ptr;
typedef __attribute__((address_space(3))) void* las_ptr;

// wave-uniform LDS base; each lane deposits 16 B at base + lane*16
__device__ __forceinline__ void load_lds16(const void* g, void* l) {
    __builtin_amdgcn_global_load_lds((gas_ptr)g, (las_ptr)l, 16, 0, 0);
}

// ---------------------------------------------------------------------------
// Fused prep: block ranges do (a) x->bf16 cast, (b) W_omega^T, (c) W1^T,
// (d) W2^T. One launch instead of four.
// ---------------------------------------------------------------------------
__device__ __forceinline__ void transpose_tile(const float* __restrict__ in,
                                               __bf16* __restrict__ out,
                                               int K, int N, int bx, int by,
                                               float (*tile)[33])
{
    const int tid = threadIdx.x;
    const int tx = tid & 31, ty = tid >> 5;       // (32, 8)
    const int n0 = bx * 32, k0 = by * 32;
    #pragma unroll
    for (int i = 0; i < 32; i += 8)
        tile[ty + i][tx] = in[(size_t)(k0 + ty + i) * N + n0 + tx];
    __syncthreads();
    #pragma unroll
    for (int i = 0; i < 32; i += 8)
        out[(size_t)(n0 + ty + i) * K + k0 + tx] = (__bf16)tile[tx][ty + i];
}

__global__ __launch_bounds__(256)
void prep_kernel(const float* __restrict__ x, __bf16* __restrict__ xb,
                 const float* __restrict__ W_omega, __bf16* __restrict__ womT,
                 const float* __restrict__ W1, __bf16* __restrict__ w1T,
                 const float* __restrict__ W2, __bf16* __restrict__ w2T)
{
    __shared__ float tile[32][33];
    const int bid = blockIdx.x;
    if (bid < 8192) {
        int i = bid * 256 + threadIdx.x;          // 2097152 float4's
        float4 v = ((const float4*)x)[i];
        bf16x4 o = { (__bf16)v.x, (__bf16)v.y, (__bf16)v.z, (__bf16)v.w };
        ((bf16x4*)xb)[i] = o;
    } else if (bid < 8448) {
        int t = bid - 8192;                       // 16 x 16
        transpose_tile(W_omega, womT, 512, 512, t & 15, t >> 4, tile);
    } else if (bid < 10496) {
        int t = bid - 8448;                       // 32 x 64
        transpose_tile(W1, w1T, 2048, 1024, t & 31, t >> 5, tile);
    } else {
        int t = bid - 10496;                      // 16 x 32
        transpose_tile(W2, w2T, 1024, 512, t & 15, t >> 4, tile);
    }
}

// ---------------------------------------------------------------------------
// bf16 MFMA GEMM (R7 structure): 128x128 tile, 4 waves, BK=64 double-buffered.
// Used for GEMM1 (MODE 0) and GEMM3 (MODE 2) where N=512 keeps 256^2 grids
// too small.
// ---------------------------------------------------------------------------
template<int MODE>
__global__ __launch_bounds__(256)
void gemm_kernel(const __bf16* __restrict__ A, const __bf16* __restrict__ Bt,
                 const float* __restrict__ bias, const __bf16* __restrict__ resid,
                 void* __restrict__ out, int M, int N, int K)
{
    __shared__ __bf16 As[2][128 * 64];
    __shared__ __bf16 Bs[2][128 * 64];

    const int tid     = threadIdx.x;
    const int tiles_n = N >> 7;                 // 4 or 8 (power of 2)
    const int ln_tn   = __ffs(tiles_n) - 1;
    const int per_m   = (M >> 7) >> 3;          // 128-row tiles per XCD

    const int xcd = blockIdx.x & 7;
    const int j   = blockIdx.x >> 3;
    const int tile_m = (xcd * per_m + (j >> ln_tn)) << 7;
    const int tile_n = (j & (tiles_n - 1)) << 7;

    const int wave = tid >> 6;
    const int lane = tid & 63;

    // staging map: lane l -> row (l>>3), chunk (l&7)^((l>>3)&7)
    const int srow = lane >> 3;                       // 0..7
    const int scol = ((lane & 7) ^ srow) << 3;        // elem offset in row

    const __bf16* Ags = A  + (size_t)(tile_m + wave * 32 + srow) * K + scol;
    const __bf16* Bgs = Bt + (size_t)(tile_n + wave * 32 + srow) * K + scol;

    const int m0 = (wave >> 1) << 6;
    const int n0 = (wave & 1) << 6;
    const int lr = lane & 15;
    const int q  = lane >> 4;
    const int l7 = lane & 7;
    const int fc0 = ((0 + q) ^ l7) << 3;   // swizzled elem offset, k-half 0
    const int fc1 = ((4 + q) ^ l7) << 3;   // swizzled elem offset, k-half 1

    f32x4 acc[4][4];
    #pragma unroll
    for (int i = 0; i < 4; ++i)
        #pragma unroll
        for (int jj = 0; jj < 4; ++jj)
            acc[i][jj] = (f32x4){0.f, 0.f, 0.f, 0.f};

    const int nIter = K >> 6;

    // prologue: stage tile 0 into buffer 0
    #pragma unroll
    for (int c = 0; c < 4; ++c) {
        load_lds16(Ags + (size_t)(c * 8) * K, &As[0][(wave * 32 + c * 8) * 64]);
        load_lds16(Bgs + (size_t)(c * 8) * K, &Bs[0][(wave * 32 + c * 8) * 64]);
    }

    for (int it = 0; it < nIter; ++it) {
        const int cur = it & 1;
        __syncthreads();   // drains prefetch issued last iter (aged thru MFMA)
        if (it + 1 < nIter) {
            const int nk = (it + 1) << 6;
            #pragma unroll
            for (int c = 0; c < 4; ++c) {
                load_lds16(Ags + nk + (size_t)(c * 8) * K, &As[cur ^ 1][(wave * 32 + c * 8) * 64]);
                load_lds16(Bgs + nk + (size_t)(c * 8) * K, &Bs[cur ^ 1][(wave * 32 + c * 8) * 64]);
            }
        }

        const __bf16* as = As[cur];
        const __bf16* bs = Bs[cur];
        // k-half 0
        {
            bf16x8 af[4], bq[4];
            #pragma unroll
            for (int i = 0; i < 4; ++i)
                af[i] = *(const bf16x8*)&as[(m0 + i * 16 + lr) * 64 + fc0];
            #pragma unroll
            for (int jj = 0; jj < 4; ++jj)
                bq[jj] = *(const bf16x8*)&bs[(n0 + jj * 16 + lr) * 64 + fc0];
            #pragma unroll
            for (int i = 0; i < 4; ++i)
                #pragma unroll
                for (int jj = 0; jj < 4; ++jj)
                    acc[i][jj] = __builtin_amdgcn_mfma_f32_16x16x32_bf16(af[i], bq[jj], acc[i][jj], 0, 0, 0);
        }
        // k-half 1
        {
            bf16x8 af[4], bq[4];
            #pragma unroll
            for (int i = 0; i < 4; ++i)
                af[i] = *(const bf16x8*)&as[(m0 + i * 16 + lr) * 64 + fc1];
            #pragma unroll
            for (int jj = 0; jj < 4; ++jj)
                bq[jj] = *(const bf16x8*)&bs[(n0 + jj * 16 + lr) * 64 + fc1];
            #pragma unroll
            for (int i = 0; i < 4; ++i)
                #pragma unroll
                for (int jj = 0; jj < 4; ++jj)
                    acc[i][jj] = __builtin_amdgcn_mfma_f32_16x16x32_bf16(af[i], bq[jj], acc[i][jj], 0, 0, 0);
        }
    }

    // epilogue — C/D layout: col = lane&15, row = (lane>>4)*4 + reg  [m89/m91]
    const int orow0 = tile_m + m0 + (q << 2);
    const int ocol0 = tile_n + n0 + lr;
    #pragma unroll
    for (int i = 0; i < 4; ++i) {
        #pragma unroll
        for (int jj = 0; jj < 4; ++jj) {
            const int col = ocol0 + jj * 16;
            const float bv = bias[col];
            #pragma unroll
            for (int r = 0; r < 4; ++r) {
                const int row = orow0 + i * 16 + r;
                float v = acc[i][jj][r] + bv;
                size_t idx = (size_t)row * N + col;
                if (MODE == 0) {
                    ((__bf16*)out)[idx] = (__bf16)v;
                } else if (MODE == 1) {
                    float g = 0.5f * v * (1.0f + erff(v * 0.70710678118654752f));
                    ((__bf16*)out)[idx] = (__bf16)g;
                } else {
                    ((float*)out)[idx] = v + (float)resid[idx];
                }
            }
        }
    }
}

// ---------------------------------------------------------------------------
// R14: 256x256-tile GEMM, 512 threads (8 waves, 2Mx4N), barrier-light groups.
//
// LDS: Abuf[2 buf][2 half][128 rows][64 k] bf16 (65536 B) + same for B =
// 128 KiB. K-tile t lives in buf(t&1). Rows are 128 B = 8 chunks of 16 B,
// physical chunk = logical ^ (row&7)  -- the VERIFIED 128^2-kernel swizzle
// (staging: lane l -> row l>>3, chunk (l&7)^(l>>3); read: (kh*4+q)^(lr&7);
// all 32 banks hit exactly 2x, conflict-free).
//
// Group g (4 phases, NO internal barriers):
//   vmcnt(0)          -- all my stages from group g-1 landed
//   s_barrier         -- publishes ALL waves' stages; also: every wave has
//                        drained its reads of buf((g+1)&1)'s old content
//                        (per-phase lgkmcnt(0) precedes barrier arrival)
//   phase 0: stage A-h0(g+1) | read af0-3 kh0 + bq kh0 (t=g) | lgkm0 | 16 MFMA
//   phase 1: stage A-h1(g+1) | read af4-7 kh0               | lgkm0 | 16 MFMA
//   phase 2: stage B-h0(g+1) | read af0-3 kh1 + bq kh1      | lgkm0 | 16 MFMA
//   phase 3: stage B-h1(g+1) | read af4-7 kh1               | lgkm0 | 16 MFMA
// Race-freedom: group-internal reads touch ONLY buf(g&1) (read-only all
// group); stages touch ONLY buf((g+1)&1), whose old content (K-tile g-1) was
// fully read+lgkm-drained by every wave before it arrived at this group's
// barrier. Waves desynchronize freely inside the group -> some waves' reads
// overlap others' MFMAs (the overlap the lockstep ring could not express);
// setprio(1) around MFMA arbitrates (T5 with a real role-split).
// A halves staged at phases 0-1 (HBM-latency lead ~3 phases), L2-hot B at
// 2-3. Frag regs ping-pong (afX/afY, bq0/bq1) to kill WAR on async ds_read
// destinations. lgkmcnt(0)+sched_barrier(0) before each MFMA cluster (rule
// #18). Accumulation k-order identical to R7-R13 -> bitwise-same numerics.
// Requires K % 128 == 0 (K=2048: 32 K-tiles, 16 group pairs).
// ---------------------------------------------------------------------------
template<int MODE>
__global__ __launch_bounds__(512, 1)
void gemm256_kernel(const __bf16* __restrict__ A, const __bf16* __restrict__ Bt,
                    const float* __restrict__ bias, void* __restrict__ out,
                    int M, int N, int K)
{
    __shared__ __bf16 As[2 * 2 * 128 * 64];   // 65536 B
    __shared__ __bf16 Bs[2 * 2 * 128 * 64];   // 65536 B

    const int tid  = threadIdx.x;
    const int wv   = tid >> 6;            // 0..7
    const int lane = tid & 63;
    const int wm   = wv >> 2;             // 0..1  (M half)
    const int wn   = wv & 3;              // 0..3  (N quarter)

    const int tiles_n = N >> 8;                    // 4 (power of 2)
    const int ln_tn   = __ffs(tiles_n) - 1;
    const int per_m   = (M >> 8) >> 3;             // 256-row tiles per XCD

    const int xcd = blockIdx.x & 7;
    const int j   = blockIdx.x >> 3;
    const int tile_m = (xcd * per_m + (j >> ln_tn)) << 8;
    const int tile_n = (j & (tiles_n - 1)) << 8;

    // --- staging constants ---------------------------------------------
    const int srow8 = lane >> 3;                          // 0..7
    const int sig8  = ((lane & 7) ^ srow8) << 3;          // elem offset
    const __bf16* AgBase = A  + (size_t)(tile_m + wv * 8 + srow8) * K + sig8;
    const __bf16* BgBase = Bt + (size_t)(tile_n + wv * 8 + srow8) * K + sig8;

    // --- fragment-read constants ---------------------------------------
    const int lr = lane & 15;
    const int q  = lane >> 4;
    const unsigned ldsA0 = (unsigned)(size_t)(las_ptr)&As[0];
    const unsigned ldsB0 = (unsigned)(size_t)(las_ptr)&Bs[0];
    const unsigned chs   = (unsigned)((q ^ (lr & 7)) << 4);   // kh0 chunk, bytes
    const unsigned aA0b0 = ldsA0 + (unsigned)(wm * 16384 + lr * 128) + chs;
    const unsigned aA1b0 = aA0b0 ^ 64;                         // kh1
    const unsigned aA0b1 = aA0b0 + 32768;
    const unsigned aA1b1 = aA1b0 + 32768;
    const unsigned aB0b0 = ldsB0 + (unsigned)((wn >> 1) * 16384 + ((wn & 1) * 64 + lr) * 128) + chs;
    const unsigned aB1b0 = aB0b0 ^ 64;
    const unsigned aB0b1 = aB0b0 + 32768;
    const unsigned aB1b1 = aB1b0 + 32768;

    f32x4 acc[8][4];
    #pragma unroll
    for (int i = 0; i < 8; ++i)
        #pragma unroll
        for (int jj = 0; jj < 4; ++jj)
            acc[i][jj] = (f32x4){0.f, 0.f, 0.f, 0.f};

    const int NKT = K >> 6;               // BK=64 K-tiles (even; 32 here)

    // stage one half-tile (2 x global_load_lds, 16 KB block-wide)
    auto stageHalf = [&](int t, int op, int h) {
        const size_t go = (size_t)(h * 128) * K + (size_t)(t << 6);
        if (op == 0) {
            __bf16* lb = As + (t & 1) * 16384 + h * 8192 + wv * 512;
            load_lds16(AgBase + go, lb);                        // rows 0-63
            load_lds16(AgBase + go + (size_t)64 * K, lb + 4096); // rows 64-127
        } else {
            __bf16* lb = Bs + (t & 1) * 16384 + h * 8192 + wv * 512;
            load_lds16(BgBase + go, lb);
            load_lds16(BgBase + go + (size_t)64 * K, lb + 4096);
        }
    };

    bf16x8 afX[4], afY[4], bq0[4], bq1[4];

#define DSR(d, a, o) asm volatile("ds_read_b128 %0, %1 offset:" o \
                                  : "=v"(d) : "v"(a))

#define PH_TAIL(AF, BQ, IB)                                                   \
    asm volatile("s_waitcnt lgkmcnt(0)" ::: "memory");                        \
    __builtin_amdgcn_sched_barrier(0);                                        \
    __builtin_amdgcn_s_setprio(1);                                            \
    _Pragma("unroll")                                                         \
    for (int i_ = 0; i_ < 4; ++i_)                                            \
        _Pragma("unroll")                                                     \
        for (int j_ = 0; j_ < 4; ++j_)                                        \
            acc[(IB) + i_][j_] = __builtin_amdgcn_mfma_f32_16x16x32_bf16(     \
                AF[i_], BQ[j_], acc[(IB) + i_][j_], 0, 0, 0);                 \
    __builtin_amdgcn_s_setprio(0);                                            \
    __builtin_amdgcn_sched_barrier(0);

#define GROUP(G, AK0, AK1, BK0, BK1)                                          \
    {                                                                         \
        asm volatile("s_waitcnt vmcnt(0)" ::: "memory");                      \
        __builtin_amdgcn_s_barrier();                                         \
        asm volatile("" ::: "memory");                                        \
        const int tn_ = (G) + 1;                                              \
        const bool st_ = tn_ < NKT;                                           \
        /* phase 0 */                                                         \
        if (st_) stageHalf(tn_, 0, 0);                                        \
        DSR(afX[0], AK0, "0");    DSR(afX[1], AK0, "2048");                   \
        DSR(afX[2], AK0, "4096"); DSR(afX[3], AK0, "6144");                   \
        DSR(bq0[0], BK0, "0");    DSR(bq0[1], BK0, "2048");                   \
        DSR(bq0[2], BK0, "4096"); DSR(bq0[3], BK0, "6144");                   \
        PH_TAIL(afX, bq0, 0)                                                  \
        /* phase 1 */                                                         \
        if (st_) stageHalf(tn_, 0, 1);                                        \
        DSR(afY[0], AK0, "8192");  DSR(afY[1], AK0, "10240");                 \
        DSR(afY[2], AK0, "12288"); DSR(afY[3], AK0, "14336");                 \
        PH_TAIL(afY, bq0, 4)                                                  \
        /* phase 2 */                                                         \
        if (st_) stageHalf(tn_, 1, 0);                                        \
        DSR(afX[0], AK1, "0");    DSR(afX[1], AK1, "2048");                   \
        DSR(afX[2], AK1, "4096"); DSR(afX[3], AK1, "6144");                   \
        DSR(bq1[0], BK1, "0");    DSR(bq1[1], BK1, "2048");                   \
        DSR(bq1[2], BK1, "4096"); DSR(bq1[3], BK1, "6144");                   \
        PH_TAIL(afX, bq1, 0)                                                  \
        /* phase 3 */                                                         \
        if (st_) stageHalf(tn_, 1, 1);                                        \
        DSR(afY[0], AK1, "8192");  DSR(afY[1], AK1, "10240");                 \
        DSR(afY[2], AK1, "12288"); DSR(afY[3], AK1, "14336");                 \
        PH_TAIL(afY, bq1, 4)                                                  \
    }

    // prologue: stage K-tile 0 into buf0 (8 loads)
    stageHalf(0, 0, 0); stageHalf(0, 0, 1);
    stageHalf(0, 1, 0); stageHalf(0, 1, 1);

    for (int g = 0; g < NKT; g += 2) {
        GROUP(g,     aA0b0, aA1b0, aB0b0, aB1b0)
        GROUP(g + 1, aA0b1, aA1b1, aB0b1, aB1b1)
    }

#undef GROUP
#undef PH_TAIL
#undef DSR

    // epilogue — C/D layout: col = lane&15, row = (lane>>4)*4 + reg
    const int orow0 = tile_m + wm * 128 + (q << 2);
    const int ocol0 = tile_n + wn * 64 + lr;
    #pragma unroll
    for (int i = 0; i < 8; ++i) {
        #pragma unroll
        for (int jj = 0; jj < 4; ++jj) {
            const int col = ocol0 + jj * 16;
            const float bv = bias[col];
            #pragma unroll
            for (int r = 0; r < 4; ++r) {
                const int row = orow0 + i * 16 + r;
                float v = acc[i][jj][r] + bv;
                if (MODE == 1) {
                    float g = 0.5f * v * (1.0f + erff(v * 0.70710678118654752f));
                    ((__bf16*)out)[(size_t)row * N + col] = (__bf16)g;
                } else {
                    ((__bf16*)out)[(size_t)row * N + col] = (__bf16)v;
                }
            }
        }
    }
}

// ---------------------------------------------------------------------------
// Per-chunk phase cumsum + rotation + running means + LayerNorm.
// ---------------------------------------------------------------------------
__global__ __launch_bounds__(512)
void scan_ln_kernel(const __bf16* __restrict__ xb, const __bf16* __restrict__ omega,
                    const float* __restrict__ log_scale,
                    const float* __restrict__ gamma, const float* __restrict__ beta,
                    __bf16* __restrict__ ctx)
{
    const int chunk = blockIdx.x;        // 0..255  (b*64 + n)
    const int d     = threadIdx.x;       // 0..511
    const int lane  = d & 63, wv = d >> 6;   // 8 waves
    const size_t base = (size_t)chunk * 64 * 512;

    const float scale = expf(log_scale[d]);
    const float g0 = gamma[d], g1 = gamma[512 + d], g2 = gamma[1024 + d], g3 = gamma[1536 + d];
    const float e0 = beta[d],  e1 = beta[512 + d],  e2 = beta[1024 + d],  e3 = beta[1536 + d];

    float phi = 0.f, scr = 0.f, sci = 0.f;
    __shared__ float red[2][16];         // [slot][8 sums | 8 sumsq]

    float om_n = (float)omega[base + d];
    float xv_n = (float)xb[base + d];

    for (int c = 0; c < 64; ++c) {
        const float om = om_n;
        const float xv = xv_n;
        if (c < 63) {
            om_n = (float)omega[base + (size_t)(c + 1) * 512 + d];
            xv_n = (float)xb[base + (size_t)(c + 1) * 512 + d];
        }
        phi += om * scale * rsqrtf((float)(c + 1));
        float sp, cp;
        __sincosf(phi, &sp, &cp);
        const float cr = xv * cp, ci = xv * sp;
        scr += cr; sci += ci;
        const float inv = 1.0f / (float)(c + 1);
        const float mr = scr * inv, mi = sci * inv;
        const float rr = mr * cp + mi * sp;
        const float ri = mi * cp - mr * sp;

        float s  = cr + ci + rr + ri;
        float s2 = cr * cr + ci * ci + rr * rr + ri * ri;
        #pragma unroll
        for (int o = 32; o > 0; o >>= 1) {
            s  += __shfl_down(s, o);
            s2 += __shfl_down(s2, o);
        }
        if (lane == 0) { red[c & 1][wv] = s; red[c & 1][8 + wv] = s2; }
        __syncthreads();
        float S = 0.f, S2 = 0.f;
        #pragma unroll
        for (int i = 0; i < 8; ++i) { S += red[c & 1][i]; S2 += red[c & 1][8 + i]; }
        const float mu   = S * (1.0f / 2048.0f);
        const float var  = S2 * (1.0f / 2048.0f) - mu * mu;
        const float rstd = rsqrtf(var + 1e-5f);

        const size_t ob = ((size_t)chunk * 64 + c) * 2048;
        ctx[ob + d]        = (__bf16)(((cr - mu) * rstd) * g0 + e0);
        ctx[ob + 512 + d]  = (__bf16)(((ci - mu) * rstd) * g1 + e1);
        ctx[ob + 1024 + d] = (__bf16)(((rr - mu) * rstd) * g2 + e2);
        ctx[ob + 1536 + d] = (__bf16)(((ri - mu) * rstd) * g3 + e3);
    }
}

// ---------------------------------------------------------------------------
// Workspace layout (bytes):
//   xb    @ 0          : 16,777,216  (16384x512 bf16)
//   womT  @ 16777216   : 524,288     (512x512 bf16, transposed)
//   w1T   @ 17301504   : 4,194,304   (1024x2048 bf16, transposed)
//   w2T   @ 21495808   : 1,048,576   (512x1024 bf16, transposed)
//   omega @ 22544384   : 16,777,216  (16384x512 bf16) — region reused as h
//   h     @ 22544384   : 33,554,432  (16384x1024 bf16)
//   ctx   @ 56098816   : 67,108,864  (16384x2048 bf16)
// ---------------------------------------------------------------------------
extern "C" void kernel_launch(void* const* d_in, const int* in_sizes, int n_in,
                              void* d_out, int out_size, void* d_ws, size_t ws_size,
                              hipStream_t stream)
{
    const float* x         = (const float*)d_in[0];
    const float* W_omega   = (const float*)d_in[1];
    const float* b_omega   = (const float*)d_in[2];
    const float* log_scale = (const float*)d_in[3];
    const float* ln_gamma  = (const float*)d_in[4];
    const float* ln_beta   = (const float*)d_in[5];
    const float* W1        = (const float*)d_in[6];
    const float* b1        = (const float*)d_in[7];
    const float* W2        = (const float*)d_in[8];
    const float* b2        = (const float*)d_in[9];
    float* out = (float*)d_out;

    char* ws = (char*)d_ws;
    __bf16* xb    = (__bf16*)(ws);
    __bf16* womT  = (__bf16*)(ws + 16777216);
    __bf16* w1T   = (__bf16*)(ws + 17301504);
    __bf16* w2T   = (__bf16*)(ws + 21495808);
    __bf16* omega = (__bf16*)(ws + 22544384);
    __bf16* hbuf  = (__bf16*)(ws + 22544384);   // reuses omega region
    __bf16* ctx   = (__bf16*)(ws + 56098816);

    // 1. fused cast + weight transposes (one launch)
    prep_kernel<<<11008, 256, 0, stream>>>(x, xb, W_omega, womT, W1, w1T, W2, w2T);

    // 2. omega = x @ W_omega + b_omega   (bf16 out)
    gemm_kernel<0><<<512, 256, 0, stream>>>(xb, womT, b_omega, nullptr, omega, 16384, 512, 512);

    // 3. chunk scan + LayerNorm -> ctx (bf16, 16384x2048)
    scan_ln_kernel<<<256, 512, 0, stream>>>(xb, omega, log_scale, ln_gamma, ln_beta, ctx);

    // 4. h = gelu(ctx @ W1 + b1)  (bf16 out) — R14 barrier-light group kernel
    gemm256_kernel<1><<<256, 512, 0, stream>>>(ctx, w1T, b1, hbuf, 16384, 1024, 2048);

    // 5. out = x + h @ W2 + b2    (fp32 out, bf16 residual)
    gemm_kernel<2><<<512, 256, 0, stream>>>(hbuf, w2T, b2, xb, out, 16384, 512, 1024);
}

// Round 6
// 260.859 us; speedup vs baseline: 1.0229x; 1.0066x over previous
//
#include <hip/hip_runtime.h>
#include <hip/hip_bf16.h>
#include <math.h>

// ---------------------------------------------------------------------------
// PSI_47931835024047: x@W_omega -> chunked phase cumsum/rotation -> LN ->
//                     W1+gelu -> W2 + residual.
// B=4 S=4096 D=512 C=64. All GEMMs bf16 MFMA.
// R15: faithful m201 8-phase port for GEMM2. Per K-tile: 4 phases of
//      {ds_read frags; stage; s_barrier; lgkmcnt(0); setprio(1); 16 MFMA;
//      setprio(0); s_barrier}. TWO barriers per phase (R14 removed them --
//      wrong deviation). Stages for tile T+1 at phases 0-1 of tile T; the
//      boundary vmcnt(0) at phase 3 waits on loads >=2 phases old (cold
//      drain, not m97's hot drain). Swizzle/staging/accumulation order
//      unchanged from R14 (verified correct).
// ---------------------------------------------------------------------------

typedef __bf16 bf16x8 __attribute__((ext_vector_type(8)));
typedef __bf16 bf16x4 __attribute__((ext_vector_type(4)));
typedef __bf16 bf16x2 __attribute__((ext_vector_type(2)));
typedef float  f32x4  __attribute__((ext_vector_type(4)));

typedef __attribute__((address_space(1))) void* gas_ptr;
typedef __attribute__((address_space(3))) void* las_ptr;

// wave-uniform LDS base; each lane deposits 16 B at base + lane*16
__device__ __forceinline__ void load_lds16(const void* g, void* l) {
    __builtin_amdgcn_global_load_lds((gas_ptr)g, (las_ptr)l, 16, 0, 0);
}

// ---------------------------------------------------------------------------
// Fused prep: block ranges do (a) x->bf16 cast, (b) W_omega^T, (c) W1^T,
// (d) W2^T. One launch instead of four.
// ---------------------------------------------------------------------------
__device__ __forceinline__ void transpose_tile(const float* __restrict__ in,
                                               __bf16* __restrict__ out,
                                               int K, int N, int bx, int by,
                                               float (*tile)[33])
{
    const int tid = threadIdx.x;
    const int tx = tid & 31, ty = tid >> 5;       // (32, 8)
    const int n0 = bx * 32, k0 = by * 32;
    #pragma unroll
    for (int i = 0; i < 32; i += 8)
        tile[ty + i][tx] = in[(size_t)(k0 + ty + i) * N + n0 + tx];
    __syncthreads();
    #pragma unroll
    for (int i = 0; i < 32; i += 8)
        out[(size_t)(n0 + ty + i) * K + k0 + tx] = (__bf16)tile[tx][ty + i];
}

__global__ __launch_bounds__(256)
void prep_kernel(const float* __restrict__ x, __bf16* __restrict__ xb,
                 const float* __restrict__ W_omega, __bf16* __restrict__ womT,
                 const float* __restrict__ W1, __bf16* __restrict__ w1T,
                 const float* __restrict__ W2, __bf16* __restrict__ w2T)
{
    __shared__ float tile[32][33];
    const int bid = blockIdx.x;
    if (bid < 8192) {
        int i = bid * 256 + threadIdx.x;          // 2097152 float4's
        float4 v = ((const float4*)x)[i];
        bf16x4 o = { (__bf16)v.x, (__bf16)v.y, (__bf16)v.z, (__bf16)v.w };
        ((bf16x4*)xb)[i] = o;
    } else if (bid < 8448) {
        int t = bid - 8192;                       // 16 x 16
        transpose_tile(W_omega, womT, 512, 512, t & 15, t >> 4, tile);
    } else if (bid < 10496) {
        int t = bid - 8448;                       // 32 x 64
        transpose_tile(W1, w1T, 2048, 1024, t & 31, t >> 5, tile);
    } else {
        int t = bid - 10496;                      // 16 x 32
        transpose_tile(W2, w2T, 1024, 512, t & 15, t >> 4, tile);
    }
}

// ---------------------------------------------------------------------------
// bf16 MFMA GEMM (R7 structure): 128x128 tile, 4 waves, BK=64 double-buffered.
// Used for GEMM1 (MODE 0) and GEMM3 (MODE 2) where N=512 keeps 256^2 grids
// too small.
// ---------------------------------------------------------------------------
template<int MODE>
__global__ __launch_bounds__(256)
void gemm_kernel(const __bf16* __restrict__ A, const __bf16* __restrict__ Bt,
                 const float* __restrict__ bias, const __bf16* __restrict__ resid,
                 void* __restrict__ out, int M, int N, int K)
{
    __shared__ __bf16 As[2][128 * 64];
    __shared__ __bf16 Bs[2][128 * 64];

    const int tid     = threadIdx.x;
    const int tiles_n = N >> 7;                 // 4 or 8 (power of 2)
    const int ln_tn   = __ffs(tiles_n) - 1;
    const int per_m   = (M >> 7) >> 3;          // 128-row tiles per XCD

    const int xcd = blockIdx.x & 7;
    const int j   = blockIdx.x >> 3;
    const int tile_m = (xcd * per_m + (j >> ln_tn)) << 7;
    const int tile_n = (j & (tiles_n - 1)) << 7;

    const int wave = tid >> 6;
    const int lane = tid & 63;

    // staging map: lane l -> row (l>>3), chunk (l&7)^((l>>3)&7)
    const int srow = lane >> 3;                       // 0..7
    const int scol = ((lane & 7) ^ srow) << 3;        // elem offset in row

    const __bf16* Ags = A  + (size_t)(tile_m + wave * 32 + srow) * K + scol;
    const __bf16* Bgs = Bt + (size_t)(tile_n + wave * 32 + srow) * K + scol;

    const int m0 = (wave >> 1) << 6;
    const int n0 = (wave & 1) << 6;
    const int lr = lane & 15;
    const int q  = lane >> 4;
    const int l7 = lane & 7;
    const int fc0 = ((0 + q) ^ l7) << 3;   // swizzled elem offset, k-half 0
    const int fc1 = ((4 + q) ^ l7) << 3;   // swizzled elem offset, k-half 1

    f32x4 acc[4][4];
    #pragma unroll
    for (int i = 0; i < 4; ++i)
        #pragma unroll
        for (int jj = 0; jj < 4; ++jj)
            acc[i][jj] = (f32x4){0.f, 0.f, 0.f, 0.f};

    const int nIter = K >> 6;

    // prologue: stage tile 0 into buffer 0
    #pragma unroll
    for (int c = 0; c < 4; ++c) {
        load_lds16(Ags + (size_t)(c * 8) * K, &As[0][(wave * 32 + c * 8) * 64]);
        load_lds16(Bgs + (size_t)(c * 8) * K, &Bs[0][(wave * 32 + c * 8) * 64]);
    }

    for (int it = 0; it < nIter; ++it) {
        const int cur = it & 1;
        __syncthreads();   // drains prefetch issued last iter (aged thru MFMA)
        if (it + 1 < nIter) {
            const int nk = (it + 1) << 6;
            #pragma unroll
            for (int c = 0; c < 4; ++c) {
                load_lds16(Ags + nk + (size_t)(c * 8) * K, &As[cur ^ 1][(wave * 32 + c * 8) * 64]);
                load_lds16(Bgs + nk + (size_t)(c * 8) * K, &Bs[cur ^ 1][(wave * 32 + c * 8) * 64]);
            }
        }

        const __bf16* as = As[cur];
        const __bf16* bs = Bs[cur];
        // k-half 0
        {
            bf16x8 af[4], bq[4];
            #pragma unroll
            for (int i = 0; i < 4; ++i)
                af[i] = *(const bf16x8*)&as[(m0 + i * 16 + lr) * 64 + fc0];
            #pragma unroll
            for (int jj = 0; jj < 4; ++jj)
                bq[jj] = *(const bf16x8*)&bs[(n0 + jj * 16 + lr) * 64 + fc0];
            #pragma unroll
            for (int i = 0; i < 4; ++i)
                #pragma unroll
                for (int jj = 0; jj < 4; ++jj)
                    acc[i][jj] = __builtin_amdgcn_mfma_f32_16x16x32_bf16(af[i], bq[jj], acc[i][jj], 0, 0, 0);
        }
        // k-half 1
        {
            bf16x8 af[4], bq[4];
            #pragma unroll
            for (int i = 0; i < 4; ++i)
                af[i] = *(const bf16x8*)&as[(m0 + i * 16 + lr) * 64 + fc1];
            #pragma unroll
            for (int jj = 0; jj < 4; ++jj)
                bq[jj] = *(const bf16x8*)&bs[(n0 + jj * 16 + lr) * 64 + fc1];
            #pragma unroll
            for (int i = 0; i < 4; ++i)
                #pragma unroll
                for (int jj = 0; jj < 4; ++jj)
                    acc[i][jj] = __builtin_amdgcn_mfma_f32_16x16x32_bf16(af[i], bq[jj], acc[i][jj], 0, 0, 0);
        }
    }

    // epilogue — C/D layout: col = lane&15, row = (lane>>4)*4 + reg  [m89/m91]
    const int orow0 = tile_m + m0 + (q << 2);
    const int ocol0 = tile_n + n0 + lr;
    #pragma unroll
    for (int i = 0; i < 4; ++i) {
        #pragma unroll
        for (int jj = 0; jj < 4; ++jj) {
            const int col = ocol0 + jj * 16;
            const float bv = bias[col];
            #pragma unroll
            for (int r = 0; r < 4; ++r) {
                const int row = orow0 + i * 16 + r;
                float v = acc[i][jj][r] + bv;
                size_t idx = (size_t)row * N + col;
                if (MODE == 0) {
                    ((__bf16*)out)[idx] = (__bf16)v;
                } else if (MODE == 1) {
                    float g = 0.5f * v * (1.0f + erff(v * 0.70710678118654752f));
                    ((__bf16*)out)[idx] = (__bf16)g;
                } else {
                    ((float*)out)[idx] = v + (float)resid[idx];
                }
            }
        }
    }
}

// ---------------------------------------------------------------------------
// R15: 256x256-tile GEMM, 512 threads (8 waves, 2Mx4N), m201 8-phase.
//
// LDS: As[2][256*64] + Bs[2][256*64] bf16 = 128 KiB; K-tile t in buf t&1.
// Rows 128 B = 8 chunks of 16 B, phys chunk = logical ^ (row&7) (verified
// conflict-free both sides, R10-R14).
//
// K-tile T (buf c=T&1), 4 phases; each phase:
//   {ds_read this phase's frags (8 or 4 x asm ds_read_b128);
//    [stage half-tiles of T+1 -> buf c^1];
//    s_barrier; lgkmcnt(0); sched_barrier(0);
//    setprio(1); 16 MFMA; setprio(0); s_barrier}
// Stages: phase 0 = A-h0,A-h1(T+1); phase 1 = B-h0,B-h1(T+1).
// Phase 3 adds vmcnt(0) before its END barrier: drains the 8 loads of T+1
// (youngest >= 2 phases old -> cold drain) and the barrier publishes them
// for T+1's phase-0 reads.
// Race-freedom: reads of buf c all phases; stages write buf c^1 whose old
// content (tile T-1) was lgkm-drained by every wave before it crossed
// T-1's final barrier. Accumulation order identical to R7-R14.
// Requires K % 128 == 0 (K=2048: 32 K-tiles).
// ---------------------------------------------------------------------------
template<int MODE>
__global__ __launch_bounds__(512, 1)
void gemm256_kernel(const __bf16* __restrict__ A, const __bf16* __restrict__ Bt,
                    const float* __restrict__ bias, void* __restrict__ out,
                    int M, int N, int K)
{
    __shared__ __bf16 As[2 * 256 * 64];   // 65536 B
    __shared__ __bf16 Bs[2 * 256 * 64];   // 65536 B

    const int tid  = threadIdx.x;
    const int wv   = tid >> 6;            // 0..7
    const int lane = tid & 63;
    const int wm   = wv >> 2;             // 0..1  (M half)
    const int wn   = wv & 3;              // 0..3  (N quarter)

    const int tiles_n = N >> 8;                    // 4 (power of 2)
    const int ln_tn   = __ffs(tiles_n) - 1;
    const int per_m   = (M >> 8) >> 3;             // 256-row tiles per XCD

    const int xcd = blockIdx.x & 7;
    const int j   = blockIdx.x >> 3;
    const int tile_m = (xcd * per_m + (j >> ln_tn)) << 8;
    const int tile_n = (j & (tiles_n - 1)) << 8;

    // --- staging constants ---------------------------------------------
    const int srow8 = lane >> 3;                          // 0..7
    const int sig8  = ((lane & 7) ^ srow8) << 3;          // elem offset
    const __bf16* AgBase = A  + (size_t)(tile_m + wv * 8 + srow8) * K + sig8;
    const __bf16* BgBase = Bt + (size_t)(tile_n + wv * 8 + srow8) * K + sig8;

    // --- fragment-read constants ---------------------------------------
    const int lr = lane & 15;
    const int q  = lane >> 4;
    const unsigned ldsA0 = (unsigned)(size_t)(las_ptr)&As[0];
    const unsigned ldsB0 = (unsigned)(size_t)(las_ptr)&Bs[0];
    const unsigned chs   = (unsigned)((q ^ (lr & 7)) << 4);   // kh0 chunk, bytes
    const unsigned aA0b0 = ldsA0 + (unsigned)(wm * 16384 + lr * 128) + chs;
    const unsigned aA1b0 = aA0b0 ^ 64;                         // kh1
    const unsigned aA0b1 = aA0b0 + 32768;
    const unsigned aA1b1 = aA1b0 + 32768;
    const unsigned aB0b0 = ldsB0 + (unsigned)((wn >> 1) * 16384 + ((wn & 1) * 64 + lr) * 128) + chs;
    const unsigned aB1b0 = aB0b0 ^ 64;
    const unsigned aB0b1 = aB0b0 + 32768;
    const unsigned aB1b1 = aB1b0 + 32768;

    f32x4 acc[8][4];
    #pragma unroll
    for (int i = 0; i < 8; ++i)
        #pragma unroll
        for (int jj = 0; jj < 4; ++jj)
            acc[i][jj] = (f32x4){0.f, 0.f, 0.f, 0.f};

    const int NKT = K >> 6;               // BK=64 K-tiles (even; 32 here)

    // stage one half-tile (2 x global_load_lds, 16 KB block-wide)
    auto stageHalf = [&](int t, int op, int h) {
        const size_t go = (size_t)(h * 128) * K + (size_t)(t << 6);
        if (op == 0) {
            __bf16* lb = As + (t & 1) * 16384 + h * 8192 + wv * 512;
            load_lds16(AgBase + go, lb);                         // rows +0..63
            load_lds16(AgBase + go + (size_t)64 * K, lb + 4096); // rows +64..127
        } else {
            __bf16* lb = Bs + (t & 1) * 16384 + h * 8192 + wv * 512;
            load_lds16(BgBase + go, lb);
            load_lds16(BgBase + go + (size_t)64 * K, lb + 4096);
        }
    };

    bf16x8 afX[4], afY[4], bq0[4], bq1[4];

#define DSR(d, a, o) asm volatile("ds_read_b128 %0, %1 offset:" o \
                                  : "=v"(d) : "v"(a))
#define SB __builtin_amdgcn_sched_barrier(0)

// barrier; lgkm0; SB; prio1; 16 MFMA; prio0; [VW]; barrier; SB
#define PH_MFMA(AF, BQ, IB, VW)                                               \
    __builtin_amdgcn_s_barrier();                                             \
    asm volatile("s_waitcnt lgkmcnt(0)" ::: "memory");                        \
    SB;                                                                       \
    __builtin_amdgcn_s_setprio(1);                                            \
    _Pragma("unroll")                                                         \
    for (int i_ = 0; i_ < 4; ++i_)                                            \
        _Pragma("unroll")                                                     \
        for (int j_ = 0; j_ < 4; ++j_)                                        \
            acc[(IB) + i_][j_] = __builtin_amdgcn_mfma_f32_16x16x32_bf16(     \
                AF[i_], BQ[j_], acc[(IB) + i_][j_], 0, 0, 0);                 \
    __builtin_amdgcn_s_setprio(0);                                            \
    VW                                                                        \
    __builtin_amdgcn_s_barrier();                                             \
    SB;

#define VM0 asm volatile("s_waitcnt vmcnt(0)" ::: "memory");

#define KTILE(T, AK0, AK1, BK0, BK1)                                          \
    {                                                                         \
        const int tn_ = (T) + 1;                                              \
        const bool st_ = tn_ < NKT;                                           \
        /* phase 0: A+B kh0 frags (i=0..3); stage A(T+1) */                   \
        DSR(afX[0], AK0, "0");    DSR(afX[1], AK0, "2048");                   \
        DSR(afX[2], AK0, "4096"); DSR(afX[3], AK0, "6144");                   \
        DSR(bq0[0], BK0, "0");    DSR(bq0[1], BK0, "2048");                   \
        DSR(bq0[2], BK0, "4096"); DSR(bq0[3], BK0, "6144");                   \
        if (st_) { stageHalf(tn_, 0, 0); stageHalf(tn_, 0, 1); }              \
        PH_MFMA(afX, bq0, 0, )                                                \
        /* phase 1: A kh0 frags (i=4..7); stage B(T+1) */                     \
        DSR(afY[0], AK0, "8192");  DSR(afY[1], AK0, "10240");                 \
        DSR(afY[2], AK0, "12288"); DSR(afY[3], AK0, "14336");                 \
        if (st_) { stageHalf(tn_, 1, 0); stageHalf(tn_, 1, 1); }              \
        PH_MFMA(afY, bq0, 4, )                                                \
        /* phase 2: A+B kh1 frags (i=0..3) */                                 \
        DSR(afX[0], AK1, "0");    DSR(afX[1], AK1, "2048");                   \
        DSR(afX[2], AK1, "4096"); DSR(afX[3], AK1, "6144");                   \
        DSR(bq1[0], BK1, "0");    DSR(bq1[1], BK1, "2048");                   \
        DSR(bq1[2], BK1, "4096"); DSR(bq1[3], BK1, "6144");                   \
        PH_MFMA(afX, bq1, 0, )                                                \
        /* phase 3: A kh1 frags (i=4..7); boundary vmcnt before end barrier */\
        DSR(afY[0], AK1, "8192");  DSR(afY[1], AK1, "10240");                 \
        DSR(afY[2], AK1, "12288"); DSR(afY[3], AK1, "14336");                 \
        PH_MFMA(afY, bq1, 4, VM0)                                             \
    }

    // prologue: stage K-tile 0 into buf0 (8 loads/thread), publish
    stageHalf(0, 0, 0); stageHalf(0, 0, 1);
    stageHalf(0, 1, 0); stageHalf(0, 1, 1);
    asm volatile("s_waitcnt vmcnt(0)" ::: "memory");
    __builtin_amdgcn_s_barrier();
    SB;

    for (int t = 0; t < NKT; t += 2) {
        KTILE(t,     aA0b0, aA1b0, aB0b0, aB1b0)
        KTILE(t + 1, aA0b1, aA1b1, aB0b1, aB1b1)
    }

#undef KTILE
#undef VM0
#undef PH_MFMA
#undef SB
#undef DSR

    // epilogue — C/D layout: col = lane&15, row = (lane>>4)*4 + reg
    const int orow0 = tile_m + wm * 128 + (q << 2);
    const int ocol0 = tile_n + wn * 64 + lr;
    #pragma unroll
    for (int i = 0; i < 8; ++i) {
        #pragma unroll
        for (int jj = 0; jj < 4; ++jj) {
            const int col = ocol0 + jj * 16;
            const float bv = bias[col];
            #pragma unroll
            for (int r = 0; r < 4; ++r) {
                const int row = orow0 + i * 16 + r;
                float v = acc[i][jj][r] + bv;
                if (MODE == 1) {
                    float g = 0.5f * v * (1.0f + erff(v * 0.70710678118654752f));
                    ((__bf16*)out)[(size_t)row * N + col] = (__bf16)g;
                } else {
                    ((__bf16*)out)[(size_t)row * N + col] = (__bf16)v;
                }
            }
        }
    }
}

// ---------------------------------------------------------------------------
// Per-chunk phase cumsum + rotation + running means + LayerNorm.
// ---------------------------------------------------------------------------
__global__ __launch_bounds__(512)
void scan_ln_kernel(const __bf16* __restrict__ xb, const __bf16* __restrict__ omega,
                    const float* __restrict__ log_scale,
                    const float* __restrict__ gamma, const float* __restrict__ beta,
                    __bf16* __restrict__ ctx)
{
    const int chunk = blockIdx.x;        // 0..255  (b*64 + n)
    const int d     = threadIdx.x;       // 0..511
    const int lane  = d & 63, wv = d >> 6;   // 8 waves
    const size_t base = (size_t)chunk * 64 * 512;

    const float scale = expf(log_scale[d]);
    const float g0 = gamma[d], g1 = gamma[512 + d], g2 = gamma[1024 + d], g3 = gamma[1536 + d];
    const float e0 = beta[d],  e1 = beta[512 + d],  e2 = beta[1024 + d],  e3 = beta[1536 + d];

    float phi = 0.f, scr = 0.f, sci = 0.f;
    __shared__ float red[2][16];         // [slot][8 sums | 8 sumsq]

    float om_n = (float)omega[base + d];
    float xv_n = (float)xb[base + d];

    for (int c = 0; c < 64; ++c) {
        const float om = om_n;
        const float xv = xv_n;
        if (c < 63) {
            om_n = (float)omega[base + (size_t)(c + 1) * 512 + d];
            xv_n = (float)xb[base + (size_t)(c + 1) * 512 + d];
        }
        phi += om * scale * rsqrtf((float)(c + 1));
        float sp, cp;
        __sincosf(phi, &sp, &cp);
        const float cr = xv * cp, ci = xv * sp;
        scr += cr; sci += ci;
        const float inv = 1.0f / (float)(c + 1);
        const float mr = scr * inv, mi = sci * inv;
        const float rr = mr * cp + mi * sp;
        const float ri = mi * cp - mr * sp;

        float s  = cr + ci + rr + ri;
        float s2 = cr * cr + ci * ci + rr * rr + ri * ri;
        #pragma unroll
        for (int o = 32; o > 0; o >>= 1) {
            s  += __shfl_down(s, o);
            s2 += __shfl_down(s2, o);
        }
        if (lane == 0) { red[c & 1][wv] = s; red[c & 1][8 + wv] = s2; }
        __syncthreads();
        float S = 0.f, S2 = 0.f;
        #pragma unroll
        for (int i = 0; i < 8; ++i) { S += red[c & 1][i]; S2 += red[c & 1][8 + i]; }
        const float mu   = S * (1.0f / 2048.0f);
        const float var  = S2 * (1.0f / 2048.0f) - mu * mu;
        const float rstd = rsqrtf(var + 1e-5f);

        const size_t ob = ((size_t)chunk * 64 + c) * 2048;
        ctx[ob + d]        = (__bf16)(((cr - mu) * rstd) * g0 + e0);
        ctx[ob + 512 + d]  = (__bf16)(((ci - mu) * rstd) * g1 + e1);
        ctx[ob + 1024 + d] = (__bf16)(((rr - mu) * rstd) * g2 + e2);
        ctx[ob + 1536 + d] = (__bf16)(((ri - mu) * rstd) * g3 + e3);
    }
}

// ---------------------------------------------------------------------------
// Workspace layout (bytes):
//   xb    @ 0          : 16,777,216  (16384x512 bf16)
//   womT  @ 16777216   : 524,288     (512x512 bf16, transposed)
//   w1T   @ 17301504   : 4,194,304   (1024x2048 bf16, transposed)
//   w2T   @ 21495808   : 1,048,576   (512x1024 bf16, transposed)
//   omega @ 22544384   : 16,777,216  (16384x512 bf16) — region reused as h
//   h     @ 22544384   : 33,554,432  (16384x1024 bf16)
//   ctx   @ 56098816   : 67,108,864  (16384x2048 bf16)
// ---------------------------------------------------------------------------
extern "C" void kernel_launch(void* const* d_in, const int* in_sizes, int n_in,
                              void* d_out, int out_size, void* d_ws, size_t ws_size,
                              hipStream_t stream)
{
    const float* x         = (const float*)d_in[0];
    const float* W_omega   = (const float*)d_in[1];
    const float* b_omega   = (const float*)d_in[2];
    const float* log_scale = (const float*)d_in[3];
    const float* ln_gamma  = (const float*)d_in[4];
    const float* ln_beta   = (const float*)d_in[5];
    const float* W1        = (const float*)d_in[6];
    const float* b1        = (const float*)d_in[7];
    const float* W2        = (const float*)d_in[8];
    const float* b2        = (const float*)d_in[9];
    float* out = (float*)d_out;

    char* ws = (char*)d_ws;
    __bf16* xb    = (__bf16*)(ws);
    __bf16* womT  = (__bf16*)(ws + 16777216);
    __bf16* w1T   = (__bf16*)(ws + 17301504);
    __bf16* w2T   = (__bf16*)(ws + 21495808);
    __bf16* omega = (__bf16*)(ws + 22544384);
    __bf16* hbuf  = (__bf16*)(ws + 22544384);   // reuses omega region
    __bf16* ctx   = (__bf16*)(ws + 56098816);

    // 1. fused cast + weight transposes (one launch)
    prep_kernel<<<11008, 256, 0, stream>>>(x, xb, W_omega, womT, W1, w1T, W2, w2T);

    // 2. omega = x @ W_omega + b_omega   (bf16 out)
    gemm_kernel<0><<<512, 256, 0, stream>>>(xb, womT, b_omega, nullptr, omega, 16384, 512, 512);

    // 3. chunk scan + LayerNorm -> ctx (bf16, 16384x2048)
    scan_ln_kernel<<<256, 512, 0, stream>>>(xb, omega, log_scale, ln_gamma, ln_beta, ctx);

    // 4. h = gelu(ctx @ W1 + b1)  (bf16 out) — R15 m201 8-phase kernel
    gemm256_kernel<1><<<256, 512, 0, stream>>>(ctx, w1T, b1, hbuf, 16384, 1024, 2048);

    // 5. out = x + h @ W2 + b2    (fp32 out, bf16 residual)
    gemm_kernel<2><<<512, 256, 0, stream>>>(hbuf, w2T, b2, xb, out, 16384, 512, 1024);
}